// Round 7
// baseline (73.627 us; speedup 1.0000x reference)
//
#include <hip/hip_runtime.h>
#include <hip/hip_bf16.h>

// Problem: GraphAttentionLayer  B=16, L=128, DIN=768, DH=300, DE=100
// Device dtypes: all float tensors fp32, adj int32, out fp32.
//
// Pipeline:
//   k_small : c[d] = sum_k elw[k]*emw[k,d]; c0; band-sparse V (<=4 weights/row)
//   k_cvt   : W (768x300 fp32) -> WT (320x768 bf16, zero-padded cols)
//   k_gemm  : h = x @ W via v_mfma_f32_16x16x32_bf16, tile 64x64, split-K=4
//   k_red   : h = sum of 4 partials ; e2[m] = h[m,:]·a[300:600]  (float4)
//   k_attn  : per (b,i): chunked-LDS ee-dot (32 rows/chunk), sigmoid*leakyrelu,
//             mask, softmax, out = h_row + att @ h[b]
//   R6->R7: ledger showed k_attn ~55-60us since R3: direct float2 ee-dot had
//   64 lanes spanning 64 cache lines per instr (request-rate bound). Chunked
//   LDS staging restores 1KB/instr coalescing at 15.4KB LDS (8 blocks/CU),
//   8 threads/j dot from LDS.

#define L 128
#define DH 300
#define DIN 768
#define DE 100
#define SPLITK 4
#define MROWS 2048
#define SL ((size_t)MROWS * DH)

typedef __bf16 bf16x8 __attribute__((ext_vector_type(8)));
typedef float f32x4 __attribute__((ext_vector_type(4)));
typedef unsigned short ushort_t;

__device__ __forceinline__ ushort_t f2bf(float f) {
    __bf16 h = (__bf16)f;
    ushort_t u;
    __builtin_memcpy(&u, &h, 2);
    return u;
}

// ---------------- k_small: c vector, c0, band-sparse V ----------------
__global__ __launch_bounds__(256) void k_small(
    const float* __restrict__ A,    // a (600,1)
    const float* __restrict__ EMW,  // edge_map_w (300,100)
    const float* __restrict__ EMB,  // edge_map_b (300,)
    const float* __restrict__ ELW,  // edge_lin_w (1,300)
    const float* __restrict__ ELB,  // edge_lin_b (1,)
    float* __restrict__ CV, float* __restrict__ C0,
    float* __restrict__ VW, int* __restrict__ VCOL)
{
    int t = threadIdx.x;
    if (blockIdx.x == 0) {
        if (t < DE) {
            float s = 0.f;
            for (int k = 0; k < DH; ++k)
                s += ELW[k] * EMW[k * DE + t];
            CV[t] = s;
        } else if (t == DE) {
            float s = 0.f;
            for (int k = 0; k < DH; ++k)
                s += ELW[k] * EMB[k];
            C0[0] = s + ELB[0];
        }
    } else {
        if (t < L) {
            int base = t * DH;
            int cm = base >> 7;           // // L, L=128
            float w0 = 0.f, w1 = 0.f, w2 = 0.f, w3 = 0.f;
            for (int j = 0; j < DH; ++j) {
                int u = ((base + j) >> 7) - cm;
                float av = A[j];
                w0 += (u == 0) ? av : 0.f;
                w1 += (u == 1) ? av : 0.f;
                w2 += (u == 2) ? av : 0.f;
                w3 += (u == 3) ? av : 0.f;
            }
            VCOL[t] = cm;
            VW[t * 4 + 0] = w0; VW[t * 4 + 1] = w1;
            VW[t * 4 + 2] = w2; VW[t * 4 + 3] = w3;
        }
    }
}

// ---------------- k_cvt: WT[c][k] = bf16(W[k][c]), c<320 (zero-pad c>=300) ----------------
__global__ __launch_bounds__(256) void k_cvt(
    const float* __restrict__ Wm, ushort_t* __restrict__ WT)
{
    __shared__ float tile[64][65];
    int k0 = blockIdx.x * 64;
    int c0 = blockIdx.y * 64;
    int t = threadIdx.x;
#pragma unroll
    for (int s = 0; s < 16; ++s) {
        int idx = t + 256 * s;         // 0..4095
        int kr = idx >> 6, cc = idx & 63;
        int c = c0 + cc;
        tile[kr][cc] = (c < DH) ? Wm[(size_t)(k0 + kr) * DH + c] : 0.f;
    }
    __syncthreads();
#pragma unroll
    for (int s = 0; s < 16; ++s) {
        int idx = t + 256 * s;
        int c = idx >> 6, kr = idx & 63;
        WT[(size_t)(c0 + c) * DIN + k0 + kr] = f2bf(tile[kr][c]);
    }
}

// ---------------- k_gemm: h = x @ W via MFMA bf16 ----------------
// grid (5 colTiles, 32 rowTiles, 4 kSlices) = 640 blocks, 256 threads (4 waves)
__global__ __launch_bounds__(256) void k_gemm(
    const float* __restrict__ X,       // (2048, 768) fp32
    const ushort_t* __restrict__ WT,   // (320, 768) bf16, transposed W
    float* __restrict__ HP)            // SPLITK x (2048*300) fp32 partials
{
    __shared__ ushort_t As[64 * 72];   // [row][k], stride 72 bf16 = 144 B
    __shared__ ushort_t Bs[64 * 72];   // [col][k]
    int t = threadIdx.x;
    int w = t >> 6;                    // wave 0..3: owns rows w*16
    int lane = t & 63;
    int lr = lane & 15;                // row/col within 16-tile
    int lk = lane >> 4;                // k-group (8 bf16 each)
    int r0 = blockIdx.y * 64;
    int c0 = blockIdx.x * 64;
    int kbase = blockIdx.z * (DIN / SPLITK);   // 192 per slice

    f32x4 acc[4];
#pragma unroll
    for (int ct = 0; ct < 4; ++ct) acc[ct] = (f32x4){0.f, 0.f, 0.f, 0.f};

    int srow = t >> 2, skq = (t & 3) * 16;

    for (int step = 0; step < 3; ++step) {
        int kk = kbase + step * 64;
        {
            const float4* xs = (const float4*)(X + (size_t)(r0 + srow) * DIN + kk + skq);
            float4 f0 = xs[0], f1 = xs[1], f2 = xs[2], f3 = xs[3];
            bf16x8 v0, v1;
            v0[0] = (__bf16)f0.x; v0[1] = (__bf16)f0.y; v0[2] = (__bf16)f0.z; v0[3] = (__bf16)f0.w;
            v0[4] = (__bf16)f1.x; v0[5] = (__bf16)f1.y; v0[6] = (__bf16)f1.z; v0[7] = (__bf16)f1.w;
            v1[0] = (__bf16)f2.x; v1[1] = (__bf16)f2.y; v1[2] = (__bf16)f2.z; v1[3] = (__bf16)f2.w;
            v1[4] = (__bf16)f3.x; v1[5] = (__bf16)f3.y; v1[6] = (__bf16)f3.z; v1[7] = (__bf16)f3.w;
            *(bf16x8*)&As[srow * 72 + skq] = v0;
            *(bf16x8*)&As[srow * 72 + skq + 8] = v1;
        }
        {
            const uint4* wp = (const uint4*)(WT + (size_t)(c0 + srow) * DIN + kk + skq);
            uint4 u0 = wp[0], u1 = wp[1];
            *(uint4*)&Bs[srow * 72 + skq] = u0;
            *(uint4*)&Bs[srow * 72 + skq + 8] = u1;
        }
        __syncthreads();
#pragma unroll
        for (int k2 = 0; k2 < 2; ++k2) {
            bf16x8 af = *(bf16x8*)&As[(w * 16 + lr) * 72 + k2 * 32 + lk * 8];
#pragma unroll
            for (int ct = 0; ct < 4; ++ct) {
                bf16x8 bf_ = *(bf16x8*)&Bs[(ct * 16 + lr) * 72 + k2 * 32 + lk * 8];
                acc[ct] = __builtin_amdgcn_mfma_f32_16x16x32_bf16(af, bf_, acc[ct], 0, 0, 0);
            }
        }
        __syncthreads();
    }
    float* outp = HP + (size_t)blockIdx.z * SL;
#pragma unroll
    for (int ct = 0; ct < 4; ++ct) {
        int col = c0 + ct * 16 + lr;
        if (col < DH) {
#pragma unroll
            for (int r = 0; r < 4; ++r) {
                int row = r0 + w * 16 + lk * 4 + r;
                outp[(size_t)row * DH + col] = acc[ct][r];
            }
        }
    }
}

// ---------------- k_red: h = sum HP[0..3]; e2 = h . a2 (float4) ----------------
__global__ __launch_bounds__(256) void k_red(
    const float* __restrict__ HP, const float* __restrict__ A,
    float* __restrict__ H, float* __restrict__ E2)
{
    int t = threadIdx.x;
    int row = blockIdx.x * 8 + (t >> 5);
    int lane = t & 31;
    const float4* a4 = (const float4*)(A + DH);
    float4* hout = (float4*)(H + (size_t)row * DH);
    float acc = 0.f;
    for (int k4 = lane; k4 < DH / 4; k4 += 32) {   // 75 float4s
        float4 hv; hv.x = 0.f; hv.y = 0.f; hv.z = 0.f; hv.w = 0.f;
#pragma unroll
        for (int z = 0; z < SPLITK; ++z) {
            float4 v = ((const float4*)(HP + (size_t)z * SL + (size_t)row * DH))[k4];
            hv.x += v.x; hv.y += v.y; hv.z += v.z; hv.w += v.w;
        }
        float4 av = a4[k4];
        hout[k4] = hv;
        acc += hv.x * av.x + hv.y * av.y + hv.z * av.z + hv.w * av.w;
    }
#pragma unroll
    for (int o = 16; o >= 1; o >>= 1) acc += __shfl_xor(acc, o);
    if (lane == 0) E2[row] = acc;
}

// ---------------- k_attn: fused attention per (b,i), chunked-LDS ee-dot ----------------
__global__ __launch_bounds__(256) void k_attn(
    const float* __restrict__ EE,  // (B,L,L,DE) fp32
    const int* __restrict__ ADJ,   // (B,L,L) int32
    const float* __restrict__ H,   // (2048, 300) fp32
    const float* __restrict__ E2,  // (2048,)
    const float* __restrict__ CV, const float* __restrict__ C0,
    const float* __restrict__ VW, const int* __restrict__ VCOL,
    float* __restrict__ OUT)
{
    __shared__ float eeb[32 * DE];   // 12.8 KB chunk: 32 j-rows
    __shared__ float hrow[DH];
    __shared__ float cl[DE];
    __shared__ float ef[L];
    __shared__ float att[L];
    __shared__ float red[4];

    int bid = blockIdx.x;           // b*128 + i
    int b = bid >> 7;
    int t = threadIdx.x;

    for (int k = t; k < DH; k += 256) hrow[k] = H[(size_t)bid * DH + k];
    if (t < DE) cl[t] = CV[t];

    int jg = t >> 3;                // 0..31: j within chunk
    int g  = t & 7;                 // 0..7: lane within j-group
    const float c0v = C0[0];

#pragma unroll
    for (int ch = 0; ch < 4; ++ch) {
        __syncthreads();            // chunk buffer reuse (first: covers hrow/cl)
        // stage chunk: ee rows [ch*32, ch*32+32), fully coalesced float4
        const float4* src = (const float4*)(EE + (size_t)bid * (L * DE) + ch * 32 * DE);
        float4* dst = (float4*)eeb;
        for (int idx = t; idx < 800; idx += 256) dst[idx] = src[idx];
        __syncthreads();
        // dot: 8 threads per j, float2 strided
        const float2* row = (const float2*)(eeb + jg * DE);
        const float2* cp = (const float2*)cl;
        float s = 0.f;
        for (int q = g; q < 50; q += 8) {
            float2 v = row[q], c2 = cp[q];
            s = fmaf(v.x, c2.x, fmaf(v.y, c2.y, s));
        }
        s += __shfl_xor(s, 1);
        s += __shfl_xor(s, 2);
        s += __shfl_xor(s, 4);
        if (g == 0) {
            int j = ch * 32 + jg;
            float ewv = 1.f / (1.f + expf(-(s + c0v)));
            int cm = VCOL[j];
            float e1 = 0.f;
#pragma unroll
            for (int u = 0; u < 4; ++u) {
                int c = cm + u; if (c > DH - 1) c = DH - 1;  // weight is 0 there
                e1 += VW[j * 4 + u] * hrow[c];
            }
            float e = e1 + E2[(size_t)b * L + j];
            e = (e > 0.f) ? e : 0.2f * e;
            ef[j] = (ADJ[(size_t)bid * L + j] > 0) ? e * ewv : -9.0e15f;
        }
    }
    __syncthreads();

    // ---- softmax over j ----
    float v = (t < L) ? ef[t] : -3.0e38f;
#pragma unroll
    for (int o = 32; o >= 1; o >>= 1) v = fmaxf(v, __shfl_xor(v, o));
    int wid = t >> 6;
    if ((t & 63) == 0) red[wid] = v;
    __syncthreads();
    float mx = fmaxf(fmaxf(red[0], red[1]), fmaxf(red[2], red[3]));
    __syncthreads();
    float p = (t < L) ? expf(ef[t] - mx) : 0.f;
    v = p;
#pragma unroll
    for (int o = 32; o >= 1; o >>= 1) v += __shfl_xor(v, o);
    if ((t & 63) == 0) red[wid] = v;
    __syncthreads();
    float denom = red[0] + red[1] + red[2] + red[3];
    if (t < L) att[t] = p / denom;
    __syncthreads();

    // ---- out = h_row + att @ h[b], 4 independent accumulators ----
    const float* Hb = H + (size_t)b * L * DH;
    for (int k = t; k < DH; k += 256) {
        float a0 = hrow[k], a1 = 0.f, a2 = 0.f, a3 = 0.f;
#pragma unroll 4
        for (int j = 0; j < L; j += 4) {
            a0 = fmaf(att[j + 0], Hb[(size_t)(j + 0) * DH + k], a0);
            a1 = fmaf(att[j + 1], Hb[(size_t)(j + 1) * DH + k], a1);
            a2 = fmaf(att[j + 2], Hb[(size_t)(j + 2) * DH + k], a2);
            a3 = fmaf(att[j + 3], Hb[(size_t)(j + 3) * DH + k], a3);
        }
        OUT[(size_t)bid * DH + k] = (a0 + a1) + (a2 + a3);
    }
}

extern "C" void kernel_launch(void* const* d_in, const int* in_sizes, int n_in,
                              void* d_out, int out_size, void* d_ws, size_t ws_size,
                              hipStream_t stream) {
    const float* X   = (const float*)d_in[0];
    const int*   ADJ = (const int*)d_in[1];
    const float* EE  = (const float*)d_in[2];
    const float* Wm  = (const float*)d_in[3];
    const float* A   = (const float*)d_in[4];
    const float* EMW = (const float*)d_in[5];
    const float* EMB = (const float*)d_in[6];
    const float* ELW = (const float*)d_in[7];
    const float* ELB = (const float*)d_in[8];
    float* OUT = (float*)d_out;

    float* ws = (float*)d_ws;
    float* HP   = ws;                    // 4 * 614400 = 2457600
    float* H    = ws + 2457600;          // 614400
    float* E2   = ws + 3072000;          // 2048
    float* CV   = ws + 3074048;          // 100
    float* C0   = ws + 3074148;          // 4 (pad)
    float* VW   = ws + 3074152;          // 512
    int*   VCOL = (int*)(ws + 3074664);  // 128
    ushort_t* WT = (ushort_t*)(ws + 3074816); // 320*768 bf16

    k_small<<<dim3(2), dim3(256), 0, stream>>>(A, EMW, EMB, ELW, ELB, CV, C0, VW, VCOL);
    k_cvt<<<dim3(12, 5), dim3(256), 0, stream>>>(Wm, WT);
    k_gemm<<<dim3(5, 32, SPLITK), dim3(256), 0, stream>>>(X, WT, HP);
    k_red<<<dim3(256), dim3(256), 0, stream>>>(HP, A, H, E2);
    k_attn<<<dim3(2048), dim3(256), 0, stream>>>(EE, ADJ, H, E2, CV, C0, VW, VCOL, OUT);
}

// Round 8
// 72.339 us; speedup vs baseline: 1.0178x; 1.0178x over previous
//
#include <hip/hip_runtime.h>
#include <hip/hip_bf16.h>

// Problem: GraphAttentionLayer  B=16, L=128, DIN=768, DH=300, DE=100
// Device dtypes: all float tensors fp32, adj int32, out fp32.
//
// Pipeline:
//   k_small : c[d] = sum_k elw[k]*emw[k,d]; c0; band-sparse V (<=4 weights/row)
//   k_cvt   : W (768x300 fp32) -> WT (320x768 bf16, zero-padded cols)
//   k_gemm  : h = x @ W via v_mfma_f32_16x16x32_bf16, tile 64x64, split-K=4
//   k_red   : h = sum of 4 partials ; e2[m] = h[m,:]·a[300:600]  (float4)
//   k_ef    : S[bid][j] = ee[bid,j,:]·c + c0  (chunked-LDS, coalesced)
//   k_sm_pv : per (b, 2 i's): e1+e2, leakyrelu, sigmoid(S), mask, softmax,
//             out = h_row + att @ h[b]  (each Hb load feeds both rows)
//   R7->R8: monolithic k_attn was 63us with NO pipe >18% busy (occ 76%) --
//   intra-block phase serialization + PV L1 thrash. Split into k_ef (EE
//   stream isolated) + k_sm_pv (IG=2 rows/block: PV L2 traffic and VMEM
//   instruction count halved). Profile now attributes EE-stream vs PV cost.

#define L 128
#define DH 300
#define DIN 768
#define DE 100
#define SPLITK 4
#define MROWS 2048
#define IG 2
#define SL ((size_t)MROWS * DH)

typedef __bf16 bf16x8 __attribute__((ext_vector_type(8)));
typedef float f32x4 __attribute__((ext_vector_type(4)));
typedef unsigned short ushort_t;

__device__ __forceinline__ ushort_t f2bf(float f) {
    __bf16 h = (__bf16)f;
    ushort_t u;
    __builtin_memcpy(&u, &h, 2);
    return u;
}

// ---------------- k_small: c vector, c0, band-sparse V ----------------
__global__ __launch_bounds__(256) void k_small(
    const float* __restrict__ A,    // a (600,1)
    const float* __restrict__ EMW,  // edge_map_w (300,100)
    const float* __restrict__ EMB,  // edge_map_b (300,)
    const float* __restrict__ ELW,  // edge_lin_w (1,300)
    const float* __restrict__ ELB,  // edge_lin_b (1,)
    float* __restrict__ CV, float* __restrict__ C0,
    float* __restrict__ VW, int* __restrict__ VCOL)
{
    int t = threadIdx.x;
    if (blockIdx.x == 0) {
        if (t < DE) {
            float s = 0.f;
            for (int k = 0; k < DH; ++k)
                s += ELW[k] * EMW[k * DE + t];
            CV[t] = s;
        } else if (t == DE) {
            float s = 0.f;
            for (int k = 0; k < DH; ++k)
                s += ELW[k] * EMB[k];
            C0[0] = s + ELB[0];
        }
    } else {
        if (t < L) {
            int base = t * DH;
            int cm = base >> 7;           // // L, L=128
            float w0 = 0.f, w1 = 0.f, w2 = 0.f, w3 = 0.f;
            for (int j = 0; j < DH; ++j) {
                int u = ((base + j) >> 7) - cm;
                float av = A[j];
                w0 += (u == 0) ? av : 0.f;
                w1 += (u == 1) ? av : 0.f;
                w2 += (u == 2) ? av : 0.f;
                w3 += (u == 3) ? av : 0.f;
            }
            VCOL[t] = cm;
            VW[t * 4 + 0] = w0; VW[t * 4 + 1] = w1;
            VW[t * 4 + 2] = w2; VW[t * 4 + 3] = w3;
        }
    }
}

// ---------------- k_cvt: WT[c][k] = bf16(W[k][c]), c<320 (zero-pad c>=300) ----------------
__global__ __launch_bounds__(256) void k_cvt(
    const float* __restrict__ Wm, ushort_t* __restrict__ WT)
{
    __shared__ float tile[64][65];
    int k0 = blockIdx.x * 64;
    int c0 = blockIdx.y * 64;
    int t = threadIdx.x;
#pragma unroll
    for (int s = 0; s < 16; ++s) {
        int idx = t + 256 * s;         // 0..4095
        int kr = idx >> 6, cc = idx & 63;
        int c = c0 + cc;
        tile[kr][cc] = (c < DH) ? Wm[(size_t)(k0 + kr) * DH + c] : 0.f;
    }
    __syncthreads();
#pragma unroll
    for (int s = 0; s < 16; ++s) {
        int idx = t + 256 * s;
        int c = idx >> 6, kr = idx & 63;
        WT[(size_t)(c0 + c) * DIN + k0 + kr] = f2bf(tile[kr][c]);
    }
}

// ---------------- k_gemm: h = x @ W via MFMA bf16 ----------------
// grid (5 colTiles, 32 rowTiles, 4 kSlices) = 640 blocks, 256 threads (4 waves)
__global__ __launch_bounds__(256) void k_gemm(
    const float* __restrict__ X,       // (2048, 768) fp32
    const ushort_t* __restrict__ WT,   // (320, 768) bf16, transposed W
    float* __restrict__ HP)            // SPLITK x (2048*300) fp32 partials
{
    __shared__ ushort_t As[64 * 72];   // [row][k], stride 72 bf16 = 144 B
    __shared__ ushort_t Bs[64 * 72];   // [col][k]
    int t = threadIdx.x;
    int w = t >> 6;                    // wave 0..3: owns rows w*16
    int lane = t & 63;
    int lr = lane & 15;                // row/col within 16-tile
    int lk = lane >> 4;                // k-group (8 bf16 each)
    int r0 = blockIdx.y * 64;
    int c0 = blockIdx.x * 64;
    int kbase = blockIdx.z * (DIN / SPLITK);   // 192 per slice

    f32x4 acc[4];
#pragma unroll
    for (int ct = 0; ct < 4; ++ct) acc[ct] = (f32x4){0.f, 0.f, 0.f, 0.f};

    int srow = t >> 2, skq = (t & 3) * 16;

    for (int step = 0; step < 3; ++step) {
        int kk = kbase + step * 64;
        {
            const float4* xs = (const float4*)(X + (size_t)(r0 + srow) * DIN + kk + skq);
            float4 f0 = xs[0], f1 = xs[1], f2 = xs[2], f3 = xs[3];
            bf16x8 v0, v1;
            v0[0] = (__bf16)f0.x; v0[1] = (__bf16)f0.y; v0[2] = (__bf16)f0.z; v0[3] = (__bf16)f0.w;
            v0[4] = (__bf16)f1.x; v0[5] = (__bf16)f1.y; v0[6] = (__bf16)f1.z; v0[7] = (__bf16)f1.w;
            v1[0] = (__bf16)f2.x; v1[1] = (__bf16)f2.y; v1[2] = (__bf16)f2.z; v1[3] = (__bf16)f2.w;
            v1[4] = (__bf16)f3.x; v1[5] = (__bf16)f3.y; v1[6] = (__bf16)f3.z; v1[7] = (__bf16)f3.w;
            *(bf16x8*)&As[srow * 72 + skq] = v0;
            *(bf16x8*)&As[srow * 72 + skq + 8] = v1;
        }
        {
            const uint4* wp = (const uint4*)(WT + (size_t)(c0 + srow) * DIN + kk + skq);
            uint4 u0 = wp[0], u1 = wp[1];
            *(uint4*)&Bs[srow * 72 + skq] = u0;
            *(uint4*)&Bs[srow * 72 + skq + 8] = u1;
        }
        __syncthreads();
#pragma unroll
        for (int k2 = 0; k2 < 2; ++k2) {
            bf16x8 af = *(bf16x8*)&As[(w * 16 + lr) * 72 + k2 * 32 + lk * 8];
#pragma unroll
            for (int ct = 0; ct < 4; ++ct) {
                bf16x8 bf_ = *(bf16x8*)&Bs[(ct * 16 + lr) * 72 + k2 * 32 + lk * 8];
                acc[ct] = __builtin_amdgcn_mfma_f32_16x16x32_bf16(af, bf_, acc[ct], 0, 0, 0);
            }
        }
        __syncthreads();
    }
    float* outp = HP + (size_t)blockIdx.z * SL;
#pragma unroll
    for (int ct = 0; ct < 4; ++ct) {
        int col = c0 + ct * 16 + lr;
        if (col < DH) {
#pragma unroll
            for (int r = 0; r < 4; ++r) {
                int row = r0 + w * 16 + lk * 4 + r;
                outp[(size_t)row * DH + col] = acc[ct][r];
            }
        }
    }
}

// ---------------- k_red: h = sum HP[0..3]; e2 = h . a2 (float4) ----------------
__global__ __launch_bounds__(256) void k_red(
    const float* __restrict__ HP, const float* __restrict__ A,
    float* __restrict__ H, float* __restrict__ E2)
{
    int t = threadIdx.x;
    int row = blockIdx.x * 8 + (t >> 5);
    int lane = t & 31;
    const float4* a4 = (const float4*)(A + DH);
    float4* hout = (float4*)(H + (size_t)row * DH);
    float acc = 0.f;
    for (int k4 = lane; k4 < DH / 4; k4 += 32) {   // 75 float4s
        float4 hv; hv.x = 0.f; hv.y = 0.f; hv.z = 0.f; hv.w = 0.f;
#pragma unroll
        for (int z = 0; z < SPLITK; ++z) {
            float4 v = ((const float4*)(HP + (size_t)z * SL + (size_t)row * DH))[k4];
            hv.x += v.x; hv.y += v.y; hv.z += v.z; hv.w += v.w;
        }
        float4 av = a4[k4];
        hout[k4] = hv;
        acc += hv.x * av.x + hv.y * av.y + hv.z * av.z + hv.w * av.w;
    }
#pragma unroll
    for (int o = 16; o >= 1; o >>= 1) acc += __shfl_xor(acc, o);
    if (lane == 0) E2[row] = acc;
}

// ---------------- k_ef: S[bid][j] = ee[bid,j,:]·c + c0 ----------------
// grid 2048 blocks x 256 threads; chunked-LDS staging (32 rows/chunk)
__global__ __launch_bounds__(256) void k_ef(
    const float* __restrict__ EE, const float* __restrict__ CV,
    const float* __restrict__ C0, float* __restrict__ S)
{
    __shared__ float eeb[32 * DE];   // 12.8 KB chunk
    __shared__ float cl[DE];
    int bid = blockIdx.x;
    int t = threadIdx.x;
    if (t < DE) cl[t] = CV[t];
    int jg = t >> 3;                 // 0..31: j within chunk
    int g  = t & 7;                  // 0..7: lane within j-group
    const float c0v = C0[0];
#pragma unroll
    for (int ch = 0; ch < 4; ++ch) {
        __syncthreads();
        const float4* src = (const float4*)(EE + (size_t)bid * (L * DE) + ch * 32 * DE);
        float4* dst = (float4*)eeb;
        for (int idx = t; idx < 800; idx += 256) dst[idx] = src[idx];
        __syncthreads();
        const float2* row = (const float2*)(eeb + jg * DE);
        const float2* cp = (const float2*)cl;
        float s = 0.f;
        for (int q = g; q < 50; q += 8) {
            float2 v = row[q], c2 = cp[q];
            s = fmaf(v.x, c2.x, fmaf(v.y, c2.y, s));
        }
        s += __shfl_xor(s, 1);
        s += __shfl_xor(s, 2);
        s += __shfl_xor(s, 4);
        if (g == 0) S[(size_t)bid * L + ch * 32 + jg] = s + c0v;
    }
}

// ---------------- k_sm_pv: ef, softmax, PV for IG=2 query rows per block ----------------
// grid 16*64 = 1024 blocks x 256 threads
__global__ __launch_bounds__(256) void k_sm_pv(
    const float* __restrict__ S, const int* __restrict__ ADJ,
    const float* __restrict__ H, const float* __restrict__ E2,
    const float* __restrict__ VW, const int* __restrict__ VCOL,
    float* __restrict__ OUT)
{
    __shared__ float hrow[IG][DH];
    __shared__ float att[IG][L];
    int blk = blockIdx.x;
    int b = blk >> 6;               // 64 i-groups per b
    int i0 = (blk & 63) * IG;
    int bid0 = b * L + i0;
    int t = threadIdx.x;

    // stage the IG query h-rows
    for (int idx = t; idx < IG * DH; idx += 256) {
        int r = idx / DH, k = idx - r * DH;
        hrow[r][k] = H[(size_t)(bid0 + r) * DH + k];
    }
    __syncthreads();

    // e_final: 256 threads = exactly IG*L pairs
    {
        int r = t >> 7, j = t & 127;
        int bid = bid0 + r;
        float s = S[(size_t)bid * L + j];
        float ewv = 1.f / (1.f + expf(-s));
        int cm = VCOL[j];
        float e1 = 0.f;
#pragma unroll
        for (int u = 0; u < 4; ++u) {
            int c = cm + u; if (c > DH - 1) c = DH - 1;   // weight is 0 there
            e1 += VW[j * 4 + u] * hrow[r][c];
        }
        float e = e1 + E2[(size_t)b * L + j];
        e = (e > 0.f) ? e : 0.2f * e;
        att[r][j] = (ADJ[(size_t)bid * L + j] > 0) ? e * ewv : -9.0e15f;
    }
    __syncthreads();

    // softmax: wave w (<IG) reduces row w across 128 entries
    {
        int w = t >> 6, lane = t & 63;
        if (w < IG) {
            float v0 = att[w][lane], v1 = att[w][lane + 64];
            float m = fmaxf(v0, v1);
#pragma unroll
            for (int o = 32; o >= 1; o >>= 1) m = fmaxf(m, __shfl_xor(m, o));
            float p0 = expf(v0 - m), p1 = expf(v1 - m);
            float sm = p0 + p1;
#pragma unroll
            for (int o = 32; o >= 1; o >>= 1) sm += __shfl_xor(sm, o);
            float inv = 1.f / sm;
            att[w][lane] = p0 * inv;
            att[w][lane + 64] = p1 * inv;
        }
    }
    __syncthreads();

    // PV: each Hb[j][k] load feeds both rows
    const float* Hb = H + (size_t)b * L * DH;
    for (int k = t; k < DH; k += 256) {
        float a0 = hrow[0][k], c0a = 0.f;
        float a1 = hrow[1][k], c1a = 0.f;
#pragma unroll 2
        for (int j = 0; j < L; j += 4) {
            float h0 = Hb[(size_t)(j + 0) * DH + k];
            float h1 = Hb[(size_t)(j + 1) * DH + k];
            float h2 = Hb[(size_t)(j + 2) * DH + k];
            float h3 = Hb[(size_t)(j + 3) * DH + k];
            a0  = fmaf(att[0][j + 0], h0, a0);
            c0a = fmaf(att[0][j + 1], h1, c0a);
            a0  = fmaf(att[0][j + 2], h2, a0);
            c0a = fmaf(att[0][j + 3], h3, c0a);
            a1  = fmaf(att[1][j + 0], h0, a1);
            c1a = fmaf(att[1][j + 1], h1, c1a);
            a1  = fmaf(att[1][j + 2], h2, a1);
            c1a = fmaf(att[1][j + 3], h3, c1a);
        }
        OUT[(size_t)(bid0 + 0) * DH + k] = a0 + c0a;
        OUT[(size_t)(bid0 + 1) * DH + k] = a1 + c1a;
    }
}

extern "C" void kernel_launch(void* const* d_in, const int* in_sizes, int n_in,
                              void* d_out, int out_size, void* d_ws, size_t ws_size,
                              hipStream_t stream) {
    const float* X   = (const float*)d_in[0];
    const int*   ADJ = (const int*)d_in[1];
    const float* EE  = (const float*)d_in[2];
    const float* Wm  = (const float*)d_in[3];
    const float* A   = (const float*)d_in[4];
    const float* EMW = (const float*)d_in[5];
    const float* EMB = (const float*)d_in[6];
    const float* ELW = (const float*)d_in[7];
    const float* ELB = (const float*)d_in[8];
    float* OUT = (float*)d_out;

    float* ws = (float*)d_ws;
    float* HP   = ws;                    // 4 * 614400 = 2457600
    float* H    = ws + 2457600;          // 614400
    float* E2   = ws + 3072000;          // 2048
    float* CV   = ws + 3074048;          // 100
    float* C0   = ws + 3074148;          // 4 (pad)
    float* VW   = ws + 3074152;          // 512
    int*   VCOL = (int*)(ws + 3074664);  // 128 (+pad 24)
    ushort_t* WT = (ushort_t*)(ws + 3074816); // 320*768 bf16 = 122880 floats
    float* Sbuf = ws + 3197696;          // 2048*128 = 262144

    k_small<<<dim3(2), dim3(256), 0, stream>>>(A, EMW, EMB, ELW, ELB, CV, C0, VW, VCOL);
    k_cvt<<<dim3(12, 5), dim3(256), 0, stream>>>(Wm, WT);
    k_gemm<<<dim3(5, 32, SPLITK), dim3(256), 0, stream>>>(X, WT, HP);
    k_red<<<dim3(256), dim3(256), 0, stream>>>(HP, A, H, E2);
    k_ef<<<dim3(2048), dim3(256), 0, stream>>>(EE, CV, C0, Sbuf);
    k_sm_pv<<<dim3(1024), dim3(256), 0, stream>>>(Sbuf, ADJ, H, E2, VW, VCOL, OUT);
}

// Round 9
// 71.837 us; speedup vs baseline: 1.0249x; 1.0070x over previous
//
#include <hip/hip_runtime.h>
#include <hip/hip_bf16.h>

// Problem: GraphAttentionLayer  B=16, L=128, DIN=768, DH=300, DE=100
// Device dtypes: all float tensors fp32, adj int32, out fp32.
//
// Pipeline:
//   k_small : c[d] = sum_k elw[k]*emw[k,d]; c0; band-sparse V (<=4 weights/row)
//   k_cvt   : W (768x300 fp32) -> WT (320x768 bf16, zero-padded cols)
//   k_gemm  : h = x @ W via v_mfma_f32_16x16x32_bf16, tile 64x64, split-K=4
//   k_red   : h = sum of 4 partials ; e2[m] = h[m,:]·a[300:600]  (float4)
//   k_ef    : S[bid][j] = ee[bid,j,:]·c + c0  (13-deep register MLP batch)
//   k_sm_pv : per (b, 2 i's): e1+e2, leakyrelu, sigmoid(S), mask, softmax,
//             out = h_row + att @ h[b]
//   R8->R9: k_ef's rolled stage loop had MLP=1 (load->vmcnt(0)->ds_write per
//   iter) -- pure latency-bound, explains occ 76%/VALU 17%/HBM 13% with flat
//   perf across R6-R8 variants. Now 13 unrolled global_load_dwordx4 to regs
//   (one latency), partial dots, LDS scatter+reduce.

#define L 128
#define DH 300
#define DIN 768
#define DE 100
#define SPLITK 4
#define MROWS 2048
#define IG 2
#define SL ((size_t)MROWS * DH)

typedef __bf16 bf16x8 __attribute__((ext_vector_type(8)));
typedef float f32x4 __attribute__((ext_vector_type(4)));
typedef unsigned short ushort_t;

__device__ __forceinline__ ushort_t f2bf(float f) {
    __bf16 h = (__bf16)f;
    ushort_t u;
    __builtin_memcpy(&u, &h, 2);
    return u;
}

// ---------------- k_small: c vector, c0, band-sparse V ----------------
__global__ __launch_bounds__(256) void k_small(
    const float* __restrict__ A,    // a (600,1)
    const float* __restrict__ EMW,  // edge_map_w (300,100)
    const float* __restrict__ EMB,  // edge_map_b (300,)
    const float* __restrict__ ELW,  // edge_lin_w (1,300)
    const float* __restrict__ ELB,  // edge_lin_b (1,)
    float* __restrict__ CV, float* __restrict__ C0,
    float* __restrict__ VW, int* __restrict__ VCOL)
{
    int t = threadIdx.x;
    if (blockIdx.x == 0) {
        if (t < DE) {
            float s = 0.f;
            for (int k = 0; k < DH; ++k)
                s += ELW[k] * EMW[k * DE + t];
            CV[t] = s;
        } else if (t == DE) {
            float s = 0.f;
            for (int k = 0; k < DH; ++k)
                s += ELW[k] * EMB[k];
            C0[0] = s + ELB[0];
        }
    } else {
        if (t < L) {
            int base = t * DH;
            int cm = base >> 7;           // // L, L=128
            float w0 = 0.f, w1 = 0.f, w2 = 0.f, w3 = 0.f;
            for (int j = 0; j < DH; ++j) {
                int u = ((base + j) >> 7) - cm;
                float av = A[j];
                w0 += (u == 0) ? av : 0.f;
                w1 += (u == 1) ? av : 0.f;
                w2 += (u == 2) ? av : 0.f;
                w3 += (u == 3) ? av : 0.f;
            }
            VCOL[t] = cm;
            VW[t * 4 + 0] = w0; VW[t * 4 + 1] = w1;
            VW[t * 4 + 2] = w2; VW[t * 4 + 3] = w3;
        }
    }
}

// ---------------- k_cvt: WT[c][k] = bf16(W[k][c]), c<320 (zero-pad c>=300) ----------------
__global__ __launch_bounds__(256) void k_cvt(
    const float* __restrict__ Wm, ushort_t* __restrict__ WT)
{
    __shared__ float tile[64][65];
    int k0 = blockIdx.x * 64;
    int c0 = blockIdx.y * 64;
    int t = threadIdx.x;
#pragma unroll
    for (int s = 0; s < 16; ++s) {
        int idx = t + 256 * s;         // 0..4095
        int kr = idx >> 6, cc = idx & 63;
        int c = c0 + cc;
        tile[kr][cc] = (c < DH) ? Wm[(size_t)(k0 + kr) * DH + c] : 0.f;
    }
    __syncthreads();
#pragma unroll
    for (int s = 0; s < 16; ++s) {
        int idx = t + 256 * s;
        int c = idx >> 6, kr = idx & 63;
        WT[(size_t)(c0 + c) * DIN + k0 + kr] = f2bf(tile[kr][c]);
    }
}

// ---------------- k_gemm: h = x @ W via MFMA bf16 ----------------
// grid (5 colTiles, 32 rowTiles, 4 kSlices) = 640 blocks, 256 threads (4 waves)
__global__ __launch_bounds__(256) void k_gemm(
    const float* __restrict__ X,       // (2048, 768) fp32
    const ushort_t* __restrict__ WT,   // (320, 768) bf16, transposed W
    float* __restrict__ HP)            // SPLITK x (2048*300) fp32 partials
{
    __shared__ ushort_t As[64 * 72];   // [row][k], stride 72 bf16 = 144 B
    __shared__ ushort_t Bs[64 * 72];   // [col][k]
    int t = threadIdx.x;
    int w = t >> 6;                    // wave 0..3: owns rows w*16
    int lane = t & 63;
    int lr = lane & 15;                // row/col within 16-tile
    int lk = lane >> 4;                // k-group (8 bf16 each)
    int r0 = blockIdx.y * 64;
    int c0 = blockIdx.x * 64;
    int kbase = blockIdx.z * (DIN / SPLITK);   // 192 per slice

    f32x4 acc[4];
#pragma unroll
    for (int ct = 0; ct < 4; ++ct) acc[ct] = (f32x4){0.f, 0.f, 0.f, 0.f};

    int srow = t >> 2, skq = (t & 3) * 16;

    for (int step = 0; step < 3; ++step) {
        int kk = kbase + step * 64;
        {
            const float4* xs = (const float4*)(X + (size_t)(r0 + srow) * DIN + kk + skq);
            float4 f0 = xs[0], f1 = xs[1], f2 = xs[2], f3 = xs[3];
            bf16x8 v0, v1;
            v0[0] = (__bf16)f0.x; v0[1] = (__bf16)f0.y; v0[2] = (__bf16)f0.z; v0[3] = (__bf16)f0.w;
            v0[4] = (__bf16)f1.x; v0[5] = (__bf16)f1.y; v0[6] = (__bf16)f1.z; v0[7] = (__bf16)f1.w;
            v1[0] = (__bf16)f2.x; v1[1] = (__bf16)f2.y; v1[2] = (__bf16)f2.z; v1[3] = (__bf16)f2.w;
            v1[4] = (__bf16)f3.x; v1[5] = (__bf16)f3.y; v1[6] = (__bf16)f3.z; v1[7] = (__bf16)f3.w;
            *(bf16x8*)&As[srow * 72 + skq] = v0;
            *(bf16x8*)&As[srow * 72 + skq + 8] = v1;
        }
        {
            const uint4* wp = (const uint4*)(WT + (size_t)(c0 + srow) * DIN + kk + skq);
            uint4 u0 = wp[0], u1 = wp[1];
            *(uint4*)&Bs[srow * 72 + skq] = u0;
            *(uint4*)&Bs[srow * 72 + skq + 8] = u1;
        }
        __syncthreads();
#pragma unroll
        for (int k2 = 0; k2 < 2; ++k2) {
            bf16x8 af = *(bf16x8*)&As[(w * 16 + lr) * 72 + k2 * 32 + lk * 8];
#pragma unroll
            for (int ct = 0; ct < 4; ++ct) {
                bf16x8 bf_ = *(bf16x8*)&Bs[(ct * 16 + lr) * 72 + k2 * 32 + lk * 8];
                acc[ct] = __builtin_amdgcn_mfma_f32_16x16x32_bf16(af, bf_, acc[ct], 0, 0, 0);
            }
        }
        __syncthreads();
    }
    float* outp = HP + (size_t)blockIdx.z * SL;
#pragma unroll
    for (int ct = 0; ct < 4; ++ct) {
        int col = c0 + ct * 16 + lr;
        if (col < DH) {
#pragma unroll
            for (int r = 0; r < 4; ++r) {
                int row = r0 + w * 16 + lk * 4 + r;
                outp[(size_t)row * DH + col] = acc[ct][r];
            }
        }
    }
}

// ---------------- k_red: h = sum HP[0..3]; e2 = h . a2 (float4) ----------------
__global__ __launch_bounds__(256) void k_red(
    const float* __restrict__ HP, const float* __restrict__ A,
    float* __restrict__ H, float* __restrict__ E2)
{
    int t = threadIdx.x;
    int row = blockIdx.x * 8 + (t >> 5);
    int lane = t & 31;
    const float4* a4 = (const float4*)(A + DH);
    float4* hout = (float4*)(H + (size_t)row * DH);
    float acc = 0.f;
    for (int k4 = lane; k4 < DH / 4; k4 += 32) {   // 75 float4s
        float4 hv; hv.x = 0.f; hv.y = 0.f; hv.z = 0.f; hv.w = 0.f;
#pragma unroll
        for (int z = 0; z < SPLITK; ++z) {
            float4 v = ((const float4*)(HP + (size_t)z * SL + (size_t)row * DH))[k4];
            hv.x += v.x; hv.y += v.y; hv.z += v.z; hv.w += v.w;
        }
        float4 av = a4[k4];
        hout[k4] = hv;
        acc += hv.x * av.x + hv.y * av.y + hv.z * av.z + hv.w * av.w;
    }
#pragma unroll
    for (int o = 16; o >= 1; o >>= 1) acc += __shfl_xor(acc, o);
    if (lane == 0) E2[row] = acc;
}

// ---------------- k_ef: S[bid][j] = ee[bid,j,:]·c + c0 ----------------
// grid 2048 blocks x 256 threads. 13-deep register-MLP load batch:
// each j-row = exactly 25 aligned float4s; flat float4 idx -> row=idx/25.
__global__ __launch_bounds__(256) void k_ef(
    const float* __restrict__ EE, const float* __restrict__ CV,
    const float* __restrict__ C0, float* __restrict__ S)
{
    __shared__ __align__(16) float cl[DE];
    __shared__ float ps[3200];       // per-float4 partial dots
    int bid = blockIdx.x;
    int t = threadIdx.x;
    const float4* src = (const float4*)(EE + (size_t)bid * (L * DE));

    // issue all 13 loads back-to-back (one exposed latency)
    float4 v[13];
#pragma unroll
    for (int s = 0; s < 12; ++s) v[s] = src[t + 256 * s];
    if (t < 128) v[12] = src[t + 3072];
    else { v[12].x = 0.f; v[12].y = 0.f; v[12].z = 0.f; v[12].w = 0.f; }

    if (t < DE) cl[t] = CV[t];
    __syncthreads();

    // partial dot per float4; p = idx%25 tracked incrementally (256%25 == 6)
    int p = t % 25;
#pragma unroll
    for (int s = 0; s < 13; ++s) {
        int idx = t + 256 * s;
        if (s < 12 || t < 128) {
            float4 c4 = *(const float4*)&cl[p * 4];
            ps[idx] = v[s].x * c4.x + v[s].y * c4.y + v[s].z * c4.z + v[s].w * c4.w;
        }
        p += 6; if (p >= 25) p -= 25;
    }
    __syncthreads();

    // reduce: 2 threads per row (13 + 12 partials), pair shfl
    int r = t >> 1, h = t & 1;
    const float* pp = ps + 25 * r + h * 13;
    float s0 = 0.f;
#pragma unroll
    for (int m = 0; m < 12; ++m) s0 += pp[m];
    if (h == 0) s0 += pp[12];
    s0 += __shfl_xor(s0, 1);
    if (h == 0) S[(size_t)bid * L + r] = s0 + C0[0];
}

// ---------------- k_sm_pv: ef, softmax, PV for IG=2 query rows per block ----------------
// grid 16*64 = 1024 blocks x 256 threads
__global__ __launch_bounds__(256) void k_sm_pv(
    const float* __restrict__ S, const int* __restrict__ ADJ,
    const float* __restrict__ H, const float* __restrict__ E2,
    const float* __restrict__ VW, const int* __restrict__ VCOL,
    float* __restrict__ OUT)
{
    __shared__ float hrow[IG][DH];
    __shared__ float att[IG][L];
    int blk = blockIdx.x;
    int b = blk >> 6;               // 64 i-groups per b
    int i0 = (blk & 63) * IG;
    int bid0 = b * L + i0;
    int t = threadIdx.x;

    for (int idx = t; idx < IG * DH; idx += 256) {
        int r = idx / DH, k = idx - r * DH;
        hrow[r][k] = H[(size_t)(bid0 + r) * DH + k];
    }
    __syncthreads();

    {
        int r = t >> 7, j = t & 127;
        int bid = bid0 + r;
        float s = S[(size_t)bid * L + j];
        float ewv = 1.f / (1.f + expf(-s));
        int cm = VCOL[j];
        float e1 = 0.f;
#pragma unroll
        for (int u = 0; u < 4; ++u) {
            int c = cm + u; if (c > DH - 1) c = DH - 1;   // weight is 0 there
            e1 += VW[j * 4 + u] * hrow[r][c];
        }
        float e = e1 + E2[(size_t)b * L + j];
        e = (e > 0.f) ? e : 0.2f * e;
        att[r][j] = (ADJ[(size_t)bid * L + j] > 0) ? e * ewv : -9.0e15f;
    }
    __syncthreads();

    {
        int w = t >> 6, lane = t & 63;
        if (w < IG) {
            float v0 = att[w][lane], v1 = att[w][lane + 64];
            float m = fmaxf(v0, v1);
#pragma unroll
            for (int o = 32; o >= 1; o >>= 1) m = fmaxf(m, __shfl_xor(m, o));
            float p0 = expf(v0 - m), p1 = expf(v1 - m);
            float sm = p0 + p1;
#pragma unroll
            for (int o = 32; o >= 1; o >>= 1) sm += __shfl_xor(sm, o);
            float inv = 1.f / sm;
            att[w][lane] = p0 * inv;
            att[w][lane + 64] = p1 * inv;
        }
    }
    __syncthreads();

    const float* Hb = H + (size_t)b * L * DH;
    for (int k = t; k < DH; k += 256) {
        float a0 = hrow[0][k], c0a = 0.f;
        float a1 = hrow[1][k], c1a = 0.f;
#pragma unroll 2
        for (int j = 0; j < L; j += 4) {
            float h0 = Hb[(size_t)(j + 0) * DH + k];
            float h1 = Hb[(size_t)(j + 1) * DH + k];
            float h2 = Hb[(size_t)(j + 2) * DH + k];
            float h3 = Hb[(size_t)(j + 3) * DH + k];
            a0  = fmaf(att[0][j + 0], h0, a0);
            c0a = fmaf(att[0][j + 1], h1, c0a);
            a0  = fmaf(att[0][j + 2], h2, a0);
            c0a = fmaf(att[0][j + 3], h3, c0a);
            a1  = fmaf(att[1][j + 0], h0, a1);
            c1a = fmaf(att[1][j + 1], h1, c1a);
            a1  = fmaf(att[1][j + 2], h2, a1);
            c1a = fmaf(att[1][j + 3], h3, c1a);
        }
        OUT[(size_t)(bid0 + 0) * DH + k] = a0 + c0a;
        OUT[(size_t)(bid0 + 1) * DH + k] = a1 + c1a;
    }
}

extern "C" void kernel_launch(void* const* d_in, const int* in_sizes, int n_in,
                              void* d_out, int out_size, void* d_ws, size_t ws_size,
                              hipStream_t stream) {
    const float* X   = (const float*)d_in[0];
    const int*   ADJ = (const int*)d_in[1];
    const float* EE  = (const float*)d_in[2];
    const float* Wm  = (const float*)d_in[3];
    const float* A   = (const float*)d_in[4];
    const float* EMW = (const float*)d_in[5];
    const float* EMB = (const float*)d_in[6];
    const float* ELW = (const float*)d_in[7];
    const float* ELB = (const float*)d_in[8];
    float* OUT = (float*)d_out;

    float* ws = (float*)d_ws;
    float* HP   = ws;                    // 4 * 614400 = 2457600
    float* H    = ws + 2457600;          // 614400
    float* E2   = ws + 3072000;          // 2048
    float* CV   = ws + 3074048;          // 100
    float* C0   = ws + 3074148;          // 4 (pad)
    float* VW   = ws + 3074152;          // 512
    int*   VCOL = (int*)(ws + 3074664);  // 128 (+pad 24)
    ushort_t* WT = (ushort_t*)(ws + 3074816); // 320*768 bf16 = 122880 floats
    float* Sbuf = ws + 3197696;          // 2048*128 = 262144

    k_small<<<dim3(2), dim3(256), 0, stream>>>(A, EMW, EMB, ELW, ELB, CV, C0, VW, VCOL);
    k_cvt<<<dim3(12, 5), dim3(256), 0, stream>>>(Wm, WT);
    k_gemm<<<dim3(5, 32, SPLITK), dim3(256), 0, stream>>>(X, WT, HP);
    k_red<<<dim3(256), dim3(256), 0, stream>>>(HP, A, H, E2);
    k_ef<<<dim3(2048), dim3(256), 0, stream>>>(EE, CV, C0, Sbuf);
    k_sm_pv<<<dim3(1024), dim3(256), 0, stream>>>(Sbuf, ADJ, H, E2, VW, VCOL, OUT);
}